// Round 1
// baseline (564.567 us; speedup 1.0000x reference)
//
#include <hip/hip_runtime.h>
#include <math.h>

#define B_ 4
#define N_ 4096
#define D_ 128
#define NS_ 16
#define HID_ 512
#define NT_ 64
#define SCALE_ 0.08838834764831843f
#define EPS_ 1e-10f

// workspace offsets (in floats)
#define OFF_K      ((size_t)0)
#define OFF_V      (OFF_K + (size_t)B_*N_*D_)
#define OFF_WTKV   (OFF_V + (size_t)B_*N_*D_)
#define OFF_WQT    (OFF_WTKV + 128*256)
#define OFF_WIHT   (OFF_WQT + 128*128)
#define OFF_WHHT   (OFF_WIHT + 128*384)
#define OFF_MW1T   (OFF_WHHT + 128*384)
#define OFF_MW2T   (OFF_MW1T + 128*512)
#define OFF_OW1T   (OFF_MW2T + 512*128)
#define OFF_OW2T   (OFF_OW1T + 256*1024)
#define OFF_SLOTS  (OFF_OW2T + 1024*128)
#define OFF_MU     (OFF_SLOTS + (size_t)B_*NS_*256)
#define OFF_WCOEF  (OFF_MU + (size_t)B_*NS_*128)
#define OFF_C      (OFF_WCOEF + (size_t)B_*128*32)
#define OFF_RS     (OFF_C + 64)
#define OFF_PART   (OFF_RS + 64)
#define OFF_ATTNU  (OFF_PART + (size_t)B_*NT_*NS_*260)

// ---------- utils ----------
__device__ __forceinline__ float blockReduceSum256(float v, float* red, int tid) {
  red[tid] = v;
  __syncthreads();
  if (tid < 128) red[tid] += red[tid + 128];
  __syncthreads();
  if (tid < 64) {
    float x = red[tid] + red[tid + 64];
    #pragma unroll
    for (int off = 32; off > 0; off >>= 1) x += __shfl_down(x, off, 64);
    if (tid == 0) red[0] = x;
  }
  __syncthreads();
  float r = red[0];
  __syncthreads();
  return r;
}

// qmu/qls -> A1/A2/c coefficients for the dots quadratic form.
// sl: LDS 256 floats (LN'd slot row). 256 threads.
__device__ __forceinline__ void slot_tail(int tid, int b, int i,
    const float* __restrict__ wqT, float* __restrict__ wcoef, float* __restrict__ cbuf,
    const float* sl, float* qm, float* ql, float* red) {
  int dout = tid & 127;
  const float* src = (tid < 128) ? sl : (sl + 128);
  float acc = 0.f;
  #pragma unroll 4
  for (int dd = 0; dd < 128; ++dd) acc = fmaf(src[dd], wqT[dd * 128 + dout], acc);
  if (tid < 128) qm[dout] = acc; else ql[dout] = acc;
  __syncthreads();
  float cp = 0.f;
  if (tid < 128) {
    float iv = expf(-2.f * ql[tid]);
    float a1 = SCALE_ * iv;
    float a2 = -2.f * SCALE_ * iv * qm[tid];
    float* wrow = &wcoef[((size_t)b * 128 + tid) * 32];
    wrow[2 * i] = a2;
    wrow[2 * i + 1] = a1;
    cp = SCALE_ * iv * qm[tid] * qm[tid];
  }
  float ctot = blockReduceSum256(cp, red, tid);
  if (tid == 0) cbuf[b * NS_ + i] = ctot;
}

// ---------- weight transposes (once) ----------
__global__ __launch_bounds__(256) void tK(
    const float* __restrict__ Wq, const float* __restrict__ Wk, const float* __restrict__ Wv,
    const float* __restrict__ Wih, const float* __restrict__ Whh,
    const float* __restrict__ mW1, const float* __restrict__ mW2,
    const float* __restrict__ oW1, const float* __restrict__ oW2,
    float* __restrict__ ws) {
  int tid = blockIdx.x * blockDim.x + threadIdx.x;
  int stride = gridDim.x * blockDim.x;
  for (int idx = tid; idx < 128 * 256; idx += stride) {
    int kk = idx >> 8, c = idx & 255;
    ws[OFF_WTKV + idx] = (c < 128) ? Wk[c * 128 + kk] : Wv[(c - 128) * 128 + kk];
  }
  for (int idx = tid; idx < 128 * 128; idx += stride) {
    int kk = idx >> 7, c = idx & 127;
    ws[OFF_WQT + idx] = Wq[c * 128 + kk];
  }
  for (int idx = tid; idx < 128 * 384; idx += stride) {
    int kk = idx / 384, g = idx % 384;
    ws[OFF_WIHT + idx] = Wih[g * 128 + kk];
    ws[OFF_WHHT + idx] = Whh[g * 128 + kk];
  }
  for (int idx = tid; idx < 128 * 512; idx += stride) {
    int kk = idx >> 9, q = idx & 511;
    ws[OFF_MW1T + idx] = mW1[q * 128 + kk];
  }
  for (int idx = tid; idx < 512 * 128; idx += stride) {
    int q = idx >> 7, d = idx & 127;
    ws[OFF_MW2T + idx] = mW2[d * 512 + q];
  }
  for (int idx = tid; idx < 256 * 1024; idx += stride) {
    int dd = idx >> 10, q = idx & 1023;
    ws[OFF_OW1T + idx] = oW1[q * 256 + dd];
  }
  for (int idx = tid; idx < 1024 * 128; idx += stride) {
    int q = idx >> 7, d = idx & 127;
    ws[OFF_OW2T + idx] = oW2[d * 1024 + q];
  }
}

// ---------- LN(inputs) + k/v GEMM ----------
__global__ __launch_bounds__(512) void k1K(const float* __restrict__ inp, const float* __restrict__ wt,
    const float* __restrict__ gin, const float* __restrict__ bin,
    float* __restrict__ kb, float* __restrict__ vb) {
  __shared__ float xs[64][129];
  __shared__ float red[64][8];
  __shared__ float mrow[64], rrow[64];
  int tid = threadIdx.x;
  int rowbase = blockIdx.x * 64;
  // stage 64x128 rows, coalesced
  #pragma unroll
  for (int it = 0; it < 4; ++it) {
    int f = tid + it * 512;
    int row = f >> 5, c4 = (f & 31) * 4;
    const float4 v = *(const float4*)&inp[(size_t)(rowbase + row) * 128 + c4];
    xs[row][c4] = v.x; xs[row][c4 + 1] = v.y; xs[row][c4 + 2] = v.z; xs[row][c4 + 3] = v.w;
  }
  __syncthreads();
  // LayerNorm per row (8 threads/row)
  int row = tid >> 3, part = tid & 7;
  float s = 0.f;
  #pragma unroll
  for (int e = 0; e < 16; ++e) s += xs[row][part * 16 + e];
  red[row][part] = s;
  __syncthreads();
  if (part == 0) {
    float m = 0.f;
    #pragma unroll
    for (int p = 0; p < 8; ++p) m += red[row][p];
    mrow[row] = m * (1.f / 128.f);
  }
  __syncthreads();
  float m = mrow[row];
  s = 0.f;
  #pragma unroll
  for (int e = 0; e < 16; ++e) { float d = xs[row][part * 16 + e] - m; s += d * d; }
  red[row][part] = s;
  __syncthreads();
  if (part == 0) {
    float v = 0.f;
    #pragma unroll
    for (int p = 0; p < 8; ++p) v += red[row][p];
    rrow[row] = rsqrtf(v * (1.f / 128.f) + 1e-5f);
  }
  __syncthreads();
  float rs = rrow[row];
  #pragma unroll
  for (int e = 0; e < 16; ++e) {
    int c = part * 16 + e;
    xs[row][c] = (xs[row][c] - m) * rs * gin[c] + bin[c];
  }
  __syncthreads();
  // GEMM: lanes = rows, each wave owns 16 output cols, 2 passes (256 cols)
  int l = tid & 63;
  int w = __builtin_amdgcn_readfirstlane(threadIdx.x >> 6);
  for (int pass = 0; pass < 2; ++pass) {
    int cbase = pass * 128 + w * 16;
    float acc[16];
    #pragma unroll
    for (int e = 0; e < 16; ++e) acc[e] = 0.f;
    #pragma unroll 4
    for (int kk = 0; kk < 128; ++kk) {
      float a = xs[l][kk];
      const float* wr = &wt[kk * 256 + cbase];  // wave-uniform -> s_load
      #pragma unroll
      for (int e = 0; e < 16; ++e) acc[e] = fmaf(a, wr[e], acc[e]);
    }
    float* outp = (cbase < 128) ? kb : vb;
    int col = cbase & 127;
    size_t o = (size_t)(rowbase + l) * 128 + col;
    #pragma unroll
    for (int e4 = 0; e4 < 4; ++e4) {
      *(float4*)&outp[o + e4 * 4] =
          make_float4(acc[e4 * 4], acc[e4 * 4 + 1], acc[e4 * 4 + 2], acc[e4 * 4 + 3]);
    }
  }
}

// ---------- initial slot prep ----------
__global__ __launch_bounds__(256) void s0K(const float* __restrict__ slots,
    const float* __restrict__ gsl, const float* __restrict__ bsl,
    const float* __restrict__ wqT, float* __restrict__ mu, float* __restrict__ wcoef,
    float* __restrict__ cbuf) {
  __shared__ float sl[256], qm[128], ql[128], red[256];
  int tid = threadIdx.x;
  int b = blockIdx.x >> 4, i = blockIdx.x & 15;
  float x = slots[(size_t)(b * NS_ + i) * 256 + tid];
  float m = blockReduceSum256(x, red, tid) * (1.f / 256.f);
  float d = x - m;
  float var = blockReduceSum256(d * d, red, tid) * (1.f / 256.f);
  float rs = rsqrtf(var + 1e-5f);
  float v = d * rs * gsl[tid] + bsl[tid];
  sl[tid] = v;
  if (tid < 128) mu[(size_t)(b * NS_ + i) * 128 + tid] = v;
  __syncthreads();
  slot_tail(tid, b, i, wqT, wcoef, cbuf, sl, qm, ql, red);
}

// ---------- main pass over tokens (per step) ----------
__global__ __launch_bounds__(512) void pK(const float* __restrict__ kb, const float* __restrict__ vb,
    const float* __restrict__ wcoef, const float* __restrict__ cbuf,
    float* __restrict__ part, float* __restrict__ attnu, int last) {
  __shared__ float ks[64][129];
  __shared__ float a1s[16][66];
  __shared__ float esum[8][64];
  int tid = threadIdx.x;
  int b = blockIdx.y, jt = blockIdx.x;
  size_t jrow = (size_t)(b * N_ + jt * 64);
  for (int f = tid; f < 2048; f += 512) {
    int row = f >> 5, c4 = (f & 31) * 4;
    float4 kv = *(const float4*)&kb[(jrow + row) * 128 + c4];
    ks[row][c4] = kv.x; ks[row][c4 + 1] = kv.y; ks[row][c4 + 2] = kv.z; ks[row][c4 + 3] = kv.w;
  }
  __syncthreads();
  // phase A: dots for 16 slots per token; lanes = tokens, wave w owns slots {2w, 2w+1}
  int l = tid & 63;
  int w = __builtin_amdgcn_readfirstlane(threadIdx.x >> 6);
  int i0 = 2 * w, i1 = 2 * w + 1;
  const float* wb = &wcoef[(size_t)b * 128 * 32];
  float d0 = cbuf[b * NS_ + i0], d1 = cbuf[b * NS_ + i1];
  #pragma unroll 4
  for (int kk = 0; kk < 128; ++kk) {
    float kv = ks[l][kk];
    float4 wv = *(const float4*)&wb[kk * 32 + 4 * w];  // wave-uniform -> s_load_dwordx4
    d0 = fmaf(fmaf(wv.y, kv, wv.x), kv, d0);
    d1 = fmaf(fmaf(wv.w, kv, wv.z), kv, d1);
  }
  float e0 = expf(-d0) + EPS_;
  float e1 = expf(-d1) + EPS_;
  esum[w][l] = e0 + e1;
  __syncthreads();
  float tot = 0.f;
  #pragma unroll
  for (int p = 0; p < 8; ++p) tot += esum[p][l];
  float a0 = e0 / tot, a1v = e1 / tot;
  a1s[i0][l] = a0;
  a1s[i1][l] = a1v;
  if (last) {
    attnu[(size_t)(b * NS_ + i0) * N_ + jt * 64 + l] = a0;
    attnu[(size_t)(b * NS_ + i1) * N_ + jt * 64 + l] = a1v;
  }
  __syncthreads();
  // phase B: partial Sv, Sv2, rowsum over this block's 64 tokens
  int i = tid >> 5, dg = tid & 31;
  float av0 = 0, av1 = 0, av2 = 0, av3 = 0, aw0 = 0, aw1 = 0, aw2 = 0, aw3 = 0, rsum = 0;
  #pragma unroll 2
  for (int j = 0; j < 64; ++j) {
    float a = a1s[i][j];
    const float4 v4 = *(const float4*)&vb[(jrow + j) * 128 + dg * 4];
    rsum += a;
    float m0 = a * v4.x, m1 = a * v4.y, m2 = a * v4.z, m3 = a * v4.w;
    av0 += m0; av1 += m1; av2 += m2; av3 += m3;
    aw0 = fmaf(m0, v4.x, aw0); aw1 = fmaf(m1, v4.y, aw1);
    aw2 = fmaf(m2, v4.z, aw2); aw3 = fmaf(m3, v4.w, aw3);
  }
  float* pr = &part[((size_t)(b * NT_ + jt) * NS_ + i) * 260];
  *(float4*)&pr[dg * 4] = make_float4(av0, av1, av2, av3);
  *(float4*)&pr[128 + dg * 4] = make_float4(aw0, aw1, aw2, aw3);
  if (dg == 0) pr[256] = rsum;
}

// ---------- per-slot update: reduce + GRU + LN + MLP + ls + next-step prep ----------
__global__ __launch_bounds__(256) void rK(const float* __restrict__ part,
    const float* __restrict__ wihT, const float* __restrict__ whhT,
    const float* __restrict__ bih, const float* __restrict__ bhh,
    const float* __restrict__ mw1T, const float* __restrict__ mw2T,
    const float* __restrict__ mb1, const float* __restrict__ mb2,
    const float* __restrict__ gmu, const float* __restrict__ bmu,
    const float* __restrict__ gsl, const float* __restrict__ bsl,
    const float* __restrict__ wqT,
    float* __restrict__ slots, float* __restrict__ mu,
    float* __restrict__ wcoef, float* __restrict__ cbuf, float* __restrict__ rowsum) {
  __shared__ float xs[128], s2[128], hm[128], giS[384], ghS[384], uu[128], h2[128];
  __shared__ float a1S[512], snew[256], qm[128], ql[128], red[256];
  int tid = threadIdx.x;
  int b = blockIdx.x >> 4, i = blockIdx.x & 15;
  size_t pbase = ((size_t)(b * NT_) * NS_ + i) * 260;
  const size_t pstr = (size_t)NS_ * 260;
  float s = 0.f;
  #pragma unroll 8
  for (int t = 0; t < 64; ++t) s += part[pbase + t * pstr + tid];
  float rp = (tid < 64) ? part[pbase + tid * pstr + 256] : 0.f;
  float rt = blockReduceSum256(rp, red, tid);
  if (tid == 0) rowsum[b * NS_ + i] = rt;
  if (tid < 128) xs[tid] = s / rt; else s2[tid - 128] = s / rt;
  if (tid < 128) hm[tid] = mu[(size_t)(b * NS_ + i) * 128 + tid];
  __syncthreads();
  // GRU gates
  for (int g = tid; g < 384; g += 256) {
    float aI = bih[g], aH = bhh[g];
    #pragma unroll 4
    for (int dd = 0; dd < 128; ++dd) {
      aI = fmaf(xs[dd], wihT[dd * 384 + g], aI);
      aH = fmaf(hm[dd], whhT[dd * 384 + g], aH);
    }
    giS[g] = aI; ghS[g] = aH;
  }
  __syncthreads();
  if (tid < 128) {
    float r = 1.f / (1.f + expf(-(giS[tid] + ghS[tid])));
    float z = 1.f / (1.f + expf(-(giS[128 + tid] + ghS[128 + tid])));
    float nn = tanhf(giS[256 + tid] + r * ghS[256 + tid]);
    uu[tid] = (1.f - z) * nn + z * hm[tid];
  }
  __syncthreads();
  // LN(u)
  float uv = (tid < 128) ? uu[tid] : 0.f;
  float m = blockReduceSum256(uv, red, tid) * (1.f / 128.f);
  float dv = (tid < 128) ? (uu[tid] - m) : 0.f;
  float var = blockReduceSum256(dv * dv, red, tid) * (1.f / 128.f);
  float rsq = rsqrtf(var + 1e-5f);
  if (tid < 128) h2[tid] = dv * rsq * gmu[tid] + bmu[tid];
  __syncthreads();
  // MLP up
  for (int q = tid; q < 512; q += 256) {
    float a = mb1[q];
    #pragma unroll 4
    for (int dd = 0; dd < 128; ++dd) a = fmaf(h2[dd], mw1T[dd * 512 + q], a);
    a1S[q] = fmaxf(a, 0.f);
  }
  __syncthreads();
  // MLP down + residual + ls
  if (tid < 128) {
    float o = mb2[tid];
    #pragma unroll 4
    for (int q = 0; q < 512; ++q) o = fmaf(a1S[q], mw2T[q * 128 + tid], o);
    float uf = uu[tid] + o;
    float arg = s2[tid] - 2.f * uf * xs[tid] + uf * uf + EPS_;
    float lsv = 0.5f * logf(fmaxf(arg, 1e-30f));
    snew[tid] = uf; snew[128 + tid] = lsv;
    size_t so = (size_t)(b * NS_ + i) * 256;
    slots[so + tid] = uf;
    slots[so + 128 + tid] = lsv;
  }
  __syncthreads();
  // next-step slot prep (LN over new slot row, q_mu/q_ls -> coefs)
  float x = snew[tid];
  float m2 = blockReduceSum256(x, red, tid) * (1.f / 256.f);
  float d2 = x - m2;
  float v2 = blockReduceSum256(d2 * d2, red, tid) * (1.f / 256.f);
  float rs2 = rsqrtf(v2 + 1e-5f);
  float slv = d2 * rs2 * gsl[tid] + bsl[tid];
  a1S[tid] = slv;  // reuse as sl buffer
  if (tid < 128) mu[(size_t)(b * NS_ + i) * 128 + tid] = slv;
  __syncthreads();
  slot_tail(tid, b, i, wqT, wcoef, cbuf, a1S, qm, ql, red);
}

// ---------- output MLP ----------
__global__ __launch_bounds__(256) void o1K(const float* __restrict__ slots,
    const float* __restrict__ ow1T, const float* __restrict__ ow2T,
    const float* __restrict__ ob1, const float* __restrict__ ob2, float* __restrict__ out) {
  __shared__ float sv[256];
  __shared__ float h1[1024];
  int tid = threadIdx.x;
  int b = blockIdx.x >> 4, i = blockIdx.x & 15;
  sv[tid] = slots[(size_t)(b * NS_ + i) * 256 + tid];
  __syncthreads();
  for (int q = tid; q < 1024; q += 256) {
    float a = ob1[q];
    #pragma unroll 4
    for (int dd = 0; dd < 256; ++dd) a = fmaf(sv[dd], ow1T[dd * 1024 + q], a);
    h1[q] = fmaxf(a, 0.f);
  }
  __syncthreads();
  if (tid < 128) {
    float o = ob2[tid];
    #pragma unroll 4
    for (int q = 0; q < 1024; ++q) o = fmaf(h1[q], ow2T[q * 128 + tid], o);
    out[(size_t)(b * NS_ + i) * 128 + tid] = o;
  }
}

// ---------- attn normalize ----------
__global__ __launch_bounds__(256) void o2K(const float* __restrict__ attnu,
    const float* __restrict__ rowsum, float* __restrict__ out) {
  int idx4 = blockIdx.x * 256 + threadIdx.x;
  int base = idx4 * 4;
  int row = base >> 12;
  float rs = rowsum[row];
  float4 v = *(const float4*)&attnu[base];
  v.x /= rs; v.y /= rs; v.z /= rs; v.w /= rs;
  *(float4*)&out[8192 + base] = v;
}

extern "C" void kernel_launch(void* const* d_in, const int* in_sizes, int n_in,
                              void* d_out, int out_size, void* d_ws, size_t ws_size,
                              hipStream_t stream) {
  const float* slots_in = (const float*)d_in[0];
  const float* inputs   = (const float*)d_in[1];
  const float* Wq  = (const float*)d_in[2];
  const float* Wk  = (const float*)d_in[3];
  const float* Wv  = (const float*)d_in[4];
  const float* Wih = (const float*)d_in[5];
  const float* Whh = (const float*)d_in[6];
  const float* bih = (const float*)d_in[7];
  const float* bhh = (const float*)d_in[8];
  const float* mW1 = (const float*)d_in[9];
  const float* mb1 = (const float*)d_in[10];
  const float* mW2 = (const float*)d_in[11];
  const float* mb2 = (const float*)d_in[12];
  const float* g_in  = (const float*)d_in[13];
  const float* be_in = (const float*)d_in[14];
  const float* g_sl  = (const float*)d_in[15];
  const float* be_sl = (const float*)d_in[16];
  const float* g_mu  = (const float*)d_in[17];
  const float* be_mu = (const float*)d_in[18];
  const float* oW1 = (const float*)d_in[19];
  const float* ob1 = (const float*)d_in[20];
  const float* oW2 = (const float*)d_in[21];
  const float* ob2 = (const float*)d_in[22];
  float* ws  = (float*)d_ws;
  float* out = (float*)d_out;
  (void)in_sizes; (void)n_in; (void)out_size; (void)ws_size;

  hipLaunchKernelGGL(tK, dim3(256), dim3(256), 0, stream,
                     Wq, Wk, Wv, Wih, Whh, mW1, mW2, oW1, oW2, ws);
  hipLaunchKernelGGL(k1K, dim3(256), dim3(512), 0, stream,
                     inputs, ws + OFF_WTKV, g_in, be_in, ws + OFF_K, ws + OFF_V);
  hipLaunchKernelGGL(s0K, dim3(64), dim3(256), 0, stream,
                     slots_in, g_sl, be_sl, ws + OFF_WQT, ws + OFF_MU, ws + OFF_WCOEF, ws + OFF_C);
  for (int s = 0; s < 4; ++s) {
    hipLaunchKernelGGL(pK, dim3(64, 4), dim3(512), 0, stream,
                       ws + OFF_K, ws + OFF_V, ws + OFF_WCOEF, ws + OFF_C,
                       ws + OFF_PART, ws + OFF_ATTNU, (s == 3) ? 1 : 0);
    hipLaunchKernelGGL(rK, dim3(64), dim3(256), 0, stream,
                       ws + OFF_PART, ws + OFF_WIHT, ws + OFF_WHHT, bih, bhh,
                       ws + OFF_MW1T, ws + OFF_MW2T, mb1, mb2, g_mu, be_mu,
                       g_sl, be_sl, ws + OFF_WQT,
                       ws + OFF_SLOTS, ws + OFF_MU, ws + OFF_WCOEF, ws + OFF_C, ws + OFF_RS);
  }
  hipLaunchKernelGGL(o1K, dim3(64), dim3(256), 0, stream,
                     ws + OFF_SLOTS, ws + OFF_OW1T, ws + OFF_OW2T, ob1, ob2, out);
  hipLaunchKernelGGL(o2K, dim3(256), dim3(256), 0, stream,
                     ws + OFF_ATTNU, ws + OFF_RS, out);
}

// Round 2
// 248.507 us; speedup vs baseline: 2.2718x; 2.2718x over previous
//
#include <hip/hip_runtime.h>
#include <math.h>

#define B_ 4
#define N_ 4096
#define D_ 128
#define NS_ 16
#define HID_ 512
#define NT_ 64
#define SCALE_ 0.08838834764831843f
#define EPS_ 1e-10f

// workspace offsets (in floats)
#define OFF_K      ((size_t)0)
#define OFF_V      (OFF_K + (size_t)B_*N_*D_)
#define OFF_WTKV   (OFF_V + (size_t)B_*N_*D_)
#define OFF_WQT    (OFF_WTKV + 128*256)
#define OFF_WC     (OFF_WQT + 128*128)
#define OFF_MW1T   (OFF_WC + 256*512)
#define OFF_MW2T   (OFF_MW1T + 128*512)
#define OFF_OW1T   (OFF_MW2T + 512*128)
#define OFF_OW2T   (OFF_OW1T + 256*1024)
#define OFF_SLOTS  (OFF_OW2T + 1024*128)
#define OFF_MU     (OFF_SLOTS + (size_t)B_*NS_*256)
#define OFF_WCOEF  (OFF_MU + (size_t)B_*NS_*128)
#define OFF_C      (OFF_WCOEF + (size_t)B_*128*32)
#define OFF_RS     (OFF_C + 64)
#define OFF_OPART  (OFF_RS + 64)
#define OFF_PART   (OFF_OPART + 64*4*128)
#define OFF_ATTNU  (OFF_PART + (size_t)B_*NT_*NS_*260)

// ---------- utils ----------
__device__ __forceinline__ float blockReduceSum256(float v, float* red, int tid) {
  red[tid] = v;
  __syncthreads();
  if (tid < 128) red[tid] += red[tid + 128];
  __syncthreads();
  if (tid < 64) {
    float x = red[tid] + red[tid + 64];
    #pragma unroll
    for (int off = 32; off > 0; off >>= 1) x += __shfl_down(x, off, 64);
    if (tid == 0) red[0] = x;
  }
  __syncthreads();
  float r = red[0];
  __syncthreads();
  return r;
}

__device__ __forceinline__ float blockReduceSum512(float v, float* red, int tid) {
  red[tid] = v;
  __syncthreads();
  if (tid < 256) red[tid] += red[tid + 256];
  __syncthreads();
  if (tid < 128) red[tid] += red[tid + 128];
  __syncthreads();
  if (tid < 64) {
    float x = red[tid] + red[tid + 64];
    #pragma unroll
    for (int off = 32; off > 0; off >>= 1) x += __shfl_down(x, off, 64);
    if (tid == 0) red[0] = x;
  }
  __syncthreads();
  float r = red[0];
  __syncthreads();
  return r;
}

// 256-thread slot tail (used by s0K only)
__device__ __forceinline__ void slot_tail(int tid, int b, int i,
    const float* __restrict__ wqT, float* __restrict__ wcoef, float* __restrict__ cbuf,
    const float* sl, float* qm, float* ql, float* red) {
  int dout = tid & 127;
  const float* src = (tid < 128) ? sl : (sl + 128);
  float acc = 0.f;
  #pragma unroll 8
  for (int dd = 0; dd < 128; ++dd) acc = fmaf(src[dd], wqT[dd * 128 + dout], acc);
  if (tid < 128) qm[dout] = acc; else ql[dout] = acc;
  __syncthreads();
  float cp = 0.f;
  if (tid < 128) {
    float iv = expf(-2.f * ql[tid]);
    float a1 = SCALE_ * iv;
    float a2 = -2.f * SCALE_ * iv * qm[tid];
    float* wrow = &wcoef[((size_t)b * 128 + tid) * 32];
    wrow[2 * i] = a2;
    wrow[2 * i + 1] = a1;
    cp = SCALE_ * iv * qm[tid] * qm[tid];
  }
  float ctot = blockReduceSum256(cp, red, tid);
  if (tid == 0) cbuf[b * NS_ + i] = ctot;
}

// ---------- weight transposes + WC build (once) ----------
__global__ __launch_bounds__(256) void tK(
    const float* __restrict__ Wq, const float* __restrict__ Wk, const float* __restrict__ Wv,
    const float* __restrict__ Wih, const float* __restrict__ Whh,
    const float* __restrict__ mW1, const float* __restrict__ mW2,
    const float* __restrict__ oW1, const float* __restrict__ oW2,
    float* __restrict__ ws) {
  int tid = blockIdx.x * blockDim.x + threadIdx.x;
  int stride = gridDim.x * blockDim.x;
  for (int idx = tid; idx < 128 * 256; idx += stride) {
    int kk = idx >> 8, c = idx & 255;
    ws[OFF_WTKV + idx] = (c < 128) ? Wk[c * 128 + kk] : Wv[(c - 128) * 128 + kk];
  }
  for (int idx = tid; idx < 128 * 128; idx += stride) {
    int kk = idx >> 7, c = idx & 127;
    ws[OFF_WQT + idx] = Wq[c * 128 + kk];
  }
  // WC[256][512]: unified GRU matvec. out = [xs|hm] @ WC
  // q<256: gi[q]+gh[q] (r,z gates); q in [256,384): gi_n; q in [384,512): gh_n
  for (int idx = tid; idx < 256 * 512; idx += stride) {
    int dd = idx >> 9, q = idx & 511;
    float v;
    if (dd < 128) {
      v = (q < 384) ? Wih[q * 128 + dd] : 0.f;
    } else {
      int dh = dd - 128;
      if (q < 256) v = Whh[q * 128 + dh];
      else if (q < 384) v = 0.f;
      else v = Whh[(q - 128) * 128 + dh];
    }
    ws[OFF_WC + idx] = v;
  }
  for (int idx = tid; idx < 128 * 512; idx += stride) {
    int kk = idx >> 9, q = idx & 511;
    ws[OFF_MW1T + idx] = mW1[q * 128 + kk];
  }
  for (int idx = tid; idx < 512 * 128; idx += stride) {
    int q = idx >> 7, d = idx & 127;
    ws[OFF_MW2T + idx] = mW2[d * 512 + q];
  }
  for (int idx = tid; idx < 256 * 1024; idx += stride) {
    int dd = idx >> 10, q = idx & 1023;
    ws[OFF_OW1T + idx] = oW1[q * 256 + dd];
  }
  for (int idx = tid; idx < 1024 * 128; idx += stride) {
    int q = idx >> 7, d = idx & 127;
    ws[OFF_OW2T + idx] = oW2[d * 1024 + q];
  }
}

// ---------- LN(inputs) + k/v GEMM ----------
__global__ __launch_bounds__(512) void k1K(const float* __restrict__ inp, const float* __restrict__ wt,
    const float* __restrict__ gin, const float* __restrict__ bin,
    float* __restrict__ kb, float* __restrict__ vb) {
  __shared__ float xs[64][129];
  __shared__ float red[64][8];
  __shared__ float mrow[64], rrow[64];
  int tid = threadIdx.x;
  int rowbase = blockIdx.x * 64;
  #pragma unroll
  for (int it = 0; it < 4; ++it) {
    int f = tid + it * 512;
    int row = f >> 5, c4 = (f & 31) * 4;
    const float4 v = *(const float4*)&inp[(size_t)(rowbase + row) * 128 + c4];
    xs[row][c4] = v.x; xs[row][c4 + 1] = v.y; xs[row][c4 + 2] = v.z; xs[row][c4 + 3] = v.w;
  }
  __syncthreads();
  int row = tid >> 3, part = tid & 7;
  float s = 0.f;
  #pragma unroll
  for (int e = 0; e < 16; ++e) s += xs[row][part * 16 + e];
  red[row][part] = s;
  __syncthreads();
  if (part == 0) {
    float m = 0.f;
    #pragma unroll
    for (int p = 0; p < 8; ++p) m += red[row][p];
    mrow[row] = m * (1.f / 128.f);
  }
  __syncthreads();
  float m = mrow[row];
  s = 0.f;
  #pragma unroll
  for (int e = 0; e < 16; ++e) { float d = xs[row][part * 16 + e] - m; s += d * d; }
  red[row][part] = s;
  __syncthreads();
  if (part == 0) {
    float v = 0.f;
    #pragma unroll
    for (int p = 0; p < 8; ++p) v += red[row][p];
    rrow[row] = rsqrtf(v * (1.f / 128.f) + 1e-5f);
  }
  __syncthreads();
  float rs = rrow[row];
  #pragma unroll
  for (int e = 0; e < 16; ++e) {
    int c = part * 16 + e;
    xs[row][c] = (xs[row][c] - m) * rs * gin[c] + bin[c];
  }
  __syncthreads();
  int l = tid & 63;
  int w = __builtin_amdgcn_readfirstlane(threadIdx.x >> 6);
  for (int pass = 0; pass < 2; ++pass) {
    int cbase = pass * 128 + w * 16;
    float acc[16];
    #pragma unroll
    for (int e = 0; e < 16; ++e) acc[e] = 0.f;
    #pragma unroll 4
    for (int kk = 0; kk < 128; ++kk) {
      float a = xs[l][kk];
      const float* wr = &wt[kk * 256 + cbase];
      #pragma unroll
      for (int e = 0; e < 16; ++e) acc[e] = fmaf(a, wr[e], acc[e]);
    }
    float* outp = (cbase < 128) ? kb : vb;
    int col = cbase & 127;
    size_t o = (size_t)(rowbase + l) * 128 + col;
    #pragma unroll
    for (int e4 = 0; e4 < 4; ++e4) {
      *(float4*)&outp[o + e4 * 4] =
          make_float4(acc[e4 * 4], acc[e4 * 4 + 1], acc[e4 * 4 + 2], acc[e4 * 4 + 3]);
    }
  }
}

// ---------- initial slot prep ----------
__global__ __launch_bounds__(256) void s0K(const float* __restrict__ slots,
    const float* __restrict__ gsl, const float* __restrict__ bsl,
    const float* __restrict__ wqT, float* __restrict__ mu, float* __restrict__ wcoef,
    float* __restrict__ cbuf) {
  __shared__ float sl[256], qm[128], ql[128], red[256];
  int tid = threadIdx.x;
  int b = blockIdx.x >> 4, i = blockIdx.x & 15;
  float x = slots[(size_t)(b * NS_ + i) * 256 + tid];
  float m = blockReduceSum256(x, red, tid) * (1.f / 256.f);
  float d = x - m;
  float var = blockReduceSum256(d * d, red, tid) * (1.f / 256.f);
  float rs = rsqrtf(var + 1e-5f);
  float v = d * rs * gsl[tid] + bsl[tid];
  sl[tid] = v;
  if (tid < 128) mu[(size_t)(b * NS_ + i) * 128 + tid] = v;
  __syncthreads();
  slot_tail(tid, b, i, wqT, wcoef, cbuf, sl, qm, ql, red);
}

// ---------- main pass over tokens (per step) ----------
__global__ __launch_bounds__(512) void pK(const float* __restrict__ kb, const float* __restrict__ vb,
    const float* __restrict__ wcoef, const float* __restrict__ cbuf,
    float* __restrict__ part, float* __restrict__ attnu, int last) {
  // phase A: buf = ksT[128][66]; phase B: buf = vs[64][132]
  __shared__ float buf[64 * 132];
  __shared__ float a1s[16][66];
  __shared__ float esum[8][64];
  int tid = threadIdx.x;
  int b = blockIdx.y, jt = blockIdx.x;
  size_t jrow = (size_t)(b * N_ + jt * 64);
  // stage K tile TRANSPOSED: ksT[kk][token]
  for (int f = tid; f < 2048; f += 512) {
    int row = f >> 5, c4 = (f & 31) * 4;
    float4 kv = *(const float4*)&kb[(jrow + row) * 128 + c4];
    buf[(c4 + 0) * 66 + row] = kv.x;
    buf[(c4 + 1) * 66 + row] = kv.y;
    buf[(c4 + 2) * 66 + row] = kv.z;
    buf[(c4 + 3) * 66 + row] = kv.w;
  }
  __syncthreads();
  // phase A: dots; lanes = tokens, wave w owns slots {2w, 2w+1}
  int l = tid & 63;
  int w = __builtin_amdgcn_readfirstlane(threadIdx.x >> 6);
  int i0 = 2 * w, i1 = 2 * w + 1;
  const float* wb = &wcoef[(size_t)b * 128 * 32];
  float d0 = cbuf[b * NS_ + i0], d1 = cbuf[b * NS_ + i1];
  #pragma unroll 8
  for (int kk = 0; kk < 128; ++kk) {
    float kv = buf[kk * 66 + l];
    float4 wv = *(const float4*)&wb[kk * 32 + 4 * w];  // wave-uniform -> s_load
    d0 = fmaf(fmaf(wv.y, kv, wv.x), kv, d0);
    d1 = fmaf(fmaf(wv.w, kv, wv.z), kv, d1);
  }
  float e0 = expf(-d0) + EPS_;
  float e1 = expf(-d1) + EPS_;
  esum[w][l] = e0 + e1;
  __syncthreads();
  float tot = 0.f;
  #pragma unroll
  for (int p = 0; p < 8; ++p) tot += esum[p][l];
  float a0 = e0 / tot, a1v = e1 / tot;
  a1s[i0][l] = a0;
  a1s[i1][l] = a1v;
  if (last) {
    attnu[(size_t)(b * NS_ + i0) * N_ + jt * 64 + l] = a0;
    attnu[(size_t)(b * NS_ + i1) * N_ + jt * 64 + l] = a1v;
  }
  __syncthreads();
  // stage V tile into the SAME buffer (K no longer needed)
  for (int f = tid; f < 2048; f += 512) {
    int row = f >> 5, c4 = (f & 31) * 4;
    float4 vv = *(const float4*)&vb[(jrow + row) * 128 + c4];
    *(float4*)&buf[row * 132 + c4] = vv;
  }
  __syncthreads();
  // phase B: partial Sv, Sv2, rowsum from LDS
  int i = tid >> 5, dg = tid & 31;
  float av0 = 0, av1 = 0, av2 = 0, av3 = 0, aw0 = 0, aw1 = 0, aw2 = 0, aw3 = 0, rsum = 0;
  #pragma unroll 4
  for (int j = 0; j < 64; ++j) {
    float a = a1s[i][j];
    const float4 v4 = *(const float4*)&buf[j * 132 + dg * 4];
    rsum += a;
    float m0 = a * v4.x, m1 = a * v4.y, m2 = a * v4.z, m3 = a * v4.w;
    av0 += m0; av1 += m1; av2 += m2; av3 += m3;
    aw0 = fmaf(m0, v4.x, aw0); aw1 = fmaf(m1, v4.y, aw1);
    aw2 = fmaf(m2, v4.z, aw2); aw3 = fmaf(m3, v4.w, aw3);
  }
  float* pr = &part[((size_t)(b * NT_ + jt) * NS_ + i) * 260];
  *(float4*)&pr[dg * 4] = make_float4(av0, av1, av2, av3);
  *(float4*)&pr[128 + dg * 4] = make_float4(aw0, aw1, aw2, aw3);
  if (dg == 0) pr[256] = rsum;
}

// ---------- per-slot update: reduce + GRU + LN + MLP + ls + next-step prep ----------
__global__ __launch_bounds__(512) void rK(const float* __restrict__ part,
    const float* __restrict__ WC,
    const float* __restrict__ bih, const float* __restrict__ bhh,
    const float* __restrict__ mw1T, const float* __restrict__ mw2T,
    const float* __restrict__ mb1, const float* __restrict__ mb2,
    const float* __restrict__ gmu, const float* __restrict__ bmu,
    const float* __restrict__ gsl, const float* __restrict__ bsl,
    const float* __restrict__ wqT,
    float* __restrict__ slots, float* __restrict__ mu,
    float* __restrict__ wcoef, float* __restrict__ cbuf, float* __restrict__ rowsum) {
  __shared__ float zS[256];   // [xs | hm]
  __shared__ float s2[128];
  __shared__ float outg[512];
  __shared__ float a1S[512];  // MLP hidden; later reused as LN'd slot row (256)
  __shared__ float uu[128], h2[128];
  __shared__ float snew[256];
  __shared__ float qm[128], ql[128];
  __shared__ float red[512];
  __shared__ float ppart[2][256];
  __shared__ float dpart[4][128];
  __shared__ float qpart[2][256];
  int tid = threadIdx.x;
  int b = blockIdx.x >> 4, i = blockIdx.x & 15;
  size_t pbase = ((size_t)(b * NT_) * NS_ + i) * 260;
  const size_t pstr = (size_t)NS_ * 260;
  // reduce 64 tile-partials (split over 2 thread halves)
  {
    int th = tid >> 8, e = tid & 255;
    float s = 0.f;
    #pragma unroll 8
    for (int t = 0; t < 32; ++t) s += part[pbase + (size_t)(th * 32 + t) * pstr + e];
    ppart[th][e] = s;
  }
  float rp = (tid < 64) ? part[pbase + (size_t)tid * pstr + 256] : 0.f;
  float rt = blockReduceSum512(rp, red, tid);  // syncs cover ppart visibility
  if (tid == 0) rowsum[b * NS_ + i] = rt;
  if (tid < 128) zS[tid] = (ppart[0][tid] + ppart[1][tid]) / rt;
  else if (tid < 256) s2[tid - 128] = (ppart[0][tid] + ppart[1][tid]) / rt;
  else if (tid < 384) zS[tid - 128] = mu[(size_t)(b * NS_ + i) * 128 + (tid - 256)];
  __syncthreads();
  // unified GRU matvec: out = [xs|hm] @ WC (256x512)
  {
    float acc = 0.f;
    #pragma unroll 8
    for (int dd = 0; dd < 256; ++dd) acc = fmaf(zS[dd], WC[dd * 512 + tid], acc);
    outg[tid] = acc;
  }
  __syncthreads();
  if (tid < 128) {
    float r = 1.f / (1.f + expf(-(outg[tid] + bih[tid] + bhh[tid])));
    float z = 1.f / (1.f + expf(-(outg[128 + tid] + bih[128 + tid] + bhh[128 + tid])));
    float nn = tanhf(outg[256 + tid] + bih[256 + tid] + r * (outg[384 + tid] + bhh[256 + tid]));
    uu[tid] = (1.f - z) * nn + z * zS[128 + tid];
  }
  __syncthreads();
  // LN(u)
  float uv = (tid < 128) ? uu[tid] : 0.f;
  float m = blockReduceSum512(uv, red, tid) * (1.f / 128.f);
  float dv = (tid < 128) ? (uu[tid] - m) : 0.f;
  float var = blockReduceSum512(dv * dv, red, tid) * (1.f / 128.f);
  float rsq = rsqrtf(var + 1e-5f);
  if (tid < 128) h2[tid] = dv * rsq * gmu[tid] + bmu[tid];
  __syncthreads();
  // MLP up (512 outputs, 1/thread)
  {
    float a = mb1[tid];
    #pragma unroll 8
    for (int dd = 0; dd < 128; ++dd) a = fmaf(h2[dd], mw1T[dd * 512 + tid], a);
    a1S[tid] = fmaxf(a, 0.f);
  }
  __syncthreads();
  // MLP down, q split 4 ways
  {
    int qg = tid >> 7, d = tid & 127;
    float dp = 0.f;
    #pragma unroll 8
    for (int qq = 0; qq < 128; ++qq)
      dp = fmaf(a1S[qg * 128 + qq], mw2T[(qg * 128 + qq) * 128 + d], dp);
    dpart[qg][d] = dp;
  }
  __syncthreads();
  if (tid < 128) {
    float o = mb2[tid] + dpart[0][tid] + dpart[1][tid] + dpart[2][tid] + dpart[3][tid];
    float uf = uu[tid] + o;
    float xsv = zS[tid];
    float arg = s2[tid] - 2.f * uf * xsv + uf * uf + EPS_;
    float lsv = 0.5f * logf(fmaxf(arg, 1e-30f));
    snew[tid] = uf; snew[128 + tid] = lsv;
    size_t so = (size_t)(b * NS_ + i) * 256;
    slots[so + tid] = uf;
    slots[so + 128 + tid] = lsv;
  }
  __syncthreads();
  // next-step LN over new slot row
  float x = (tid < 256) ? snew[tid] : 0.f;
  float m2 = blockReduceSum512(x, red, tid) * (1.f / 256.f);
  float d2 = (tid < 256) ? (snew[tid] - m2) : 0.f;
  float v2 = blockReduceSum512(d2 * d2, red, tid) * (1.f / 256.f);
  float rs2 = rsqrtf(v2 + 1e-5f);
  if (tid < 256) {
    float slv = d2 * rs2 * gsl[tid] + bsl[tid];
    a1S[tid] = slv;
    if (tid < 128) mu[(size_t)(b * NS_ + i) * 128 + tid] = slv;
  }
  __syncthreads();
  // slot tail, K split 2 ways
  {
    int kg = tid >> 8, oq = tid & 255;
    const float* src = (oq < 128) ? a1S : (a1S + 128);
    int dout = oq & 127;
    float acc = 0.f;
    #pragma unroll 8
    for (int dd = 0; dd < 64; ++dd)
      acc = fmaf(src[kg * 64 + dd], wqT[(kg * 64 + dd) * 128 + dout], acc);
    qpart[kg][oq] = acc;
  }
  __syncthreads();
  if (tid < 256) {
    float q = qpart[0][tid] + qpart[1][tid];
    if (tid < 128) qm[tid] = q; else ql[tid - 128] = q;
  }
  __syncthreads();
  float cp = 0.f;
  if (tid < 128) {
    float iv = expf(-2.f * ql[tid]);
    float a1 = SCALE_ * iv;
    float a2 = -2.f * SCALE_ * iv * qm[tid];
    float* wrow = &wcoef[((size_t)b * 128 + tid) * 32];
    wrow[2 * i] = a2;
    wrow[2 * i + 1] = a1;
    cp = SCALE_ * iv * qm[tid] * qm[tid];
  }
  float ctot = blockReduceSum512(cp, red, tid);
  if (tid == 0) cbuf[b * NS_ + i] = ctot;
}

// ---------- output MLP: grid 256 = (b,i) x 4 N-chunks ----------
__global__ __launch_bounds__(256) void o1K(const float* __restrict__ slots,
    const float* __restrict__ ow1T, const float* __restrict__ ow2T,
    const float* __restrict__ ob1, float* __restrict__ opart) {
  __shared__ float sv[256];
  __shared__ float up[4][256];
  __shared__ float h1s[256];
  __shared__ float dpart[2][128];
  int tid = threadIdx.x;
  int blk = blockIdx.x;
  int bi = blk >> 2, c = blk & 3;
  sv[tid] = slots[(size_t)bi * 256 + tid];
  __syncthreads();
  // up: K=256 split 4 ways, each thread float4 of outputs -> 4 chains
  {
    int kg = tid >> 6, q4 = tid & 63;
    float ax = 0.f, ay = 0.f, az = 0.f, aw = 0.f;
    #pragma unroll 8
    for (int dd = 0; dd < 64; ++dd) {
      float a = sv[kg * 64 + dd];
      const float4 w4 = *(const float4*)&ow1T[(size_t)(kg * 64 + dd) * 1024 + c * 256 + q4 * 4];
      ax = fmaf(a, w4.x, ax); ay = fmaf(a, w4.y, ay);
      az = fmaf(a, w4.z, az); aw = fmaf(a, w4.w, aw);
    }
    *(float4*)&up[kg][q4 * 4] = make_float4(ax, ay, az, aw);
  }
  __syncthreads();
  h1s[tid] = fmaxf(up[0][tid] + up[1][tid] + up[2][tid] + up[3][tid] + ob1[c * 256 + tid], 0.f);
  __syncthreads();
  // down partial: q chunk of 256 split 2 ways
  {
    int qg = tid >> 7, d = tid & 127;
    float dp = 0.f;
    #pragma unroll 8
    for (int qq = 0; qq < 128; ++qq)
      dp = fmaf(h1s[qg * 128 + qq], ow2T[(size_t)(c * 256 + qg * 128 + qq) * 128 + d], dp);
    dpart[qg][d] = dp;
  }
  __syncthreads();
  if (tid < 128) opart[(size_t)blk * 128 + tid] = dpart[0][tid] + dpart[1][tid];
}

// ---------- attn normalize + slots-out merge ----------
__global__ __launch_bounds__(256) void o2K(const float* __restrict__ attnu,
    const float* __restrict__ rowsum, const float* __restrict__ opart,
    const float* __restrict__ ob2, float* __restrict__ out) {
  int tid = threadIdx.x;
  if (blockIdx.x < 256) {
    int idx4 = blockIdx.x * 256 + tid;
    int base = idx4 * 4;
    int row = base >> 12;
    float rs = rowsum[row];
    float4 v = *(const float4*)&attnu[base];
    v.x /= rs; v.y /= rs; v.z /= rs; v.w /= rs;
    *(float4*)&out[8192 + base] = v;
  } else {
    int idx = (blockIdx.x - 256) * 256 + tid;  // 8192 slot-out elems
    int bi = idx >> 7, d = idx & 127;
    out[idx] = ob2[d] + opart[(size_t)(bi * 4 + 0) * 128 + d]
                      + opart[(size_t)(bi * 4 + 1) * 128 + d]
                      + opart[(size_t)(bi * 4 + 2) * 128 + d]
                      + opart[(size_t)(bi * 4 + 3) * 128 + d];
  }
}

extern "C" void kernel_launch(void* const* d_in, const int* in_sizes, int n_in,
                              void* d_out, int out_size, void* d_ws, size_t ws_size,
                              hipStream_t stream) {
  const float* slots_in = (const float*)d_in[0];
  const float* inputs   = (const float*)d_in[1];
  const float* Wq  = (const float*)d_in[2];
  const float* Wk  = (const float*)d_in[3];
  const float* Wv  = (const float*)d_in[4];
  const float* Wih = (const float*)d_in[5];
  const float* Whh = (const float*)d_in[6];
  const float* bih = (const float*)d_in[7];
  const float* bhh = (const float*)d_in[8];
  const float* mW1 = (const float*)d_in[9];
  const float* mb1 = (const float*)d_in[10];
  const float* mW2 = (const float*)d_in[11];
  const float* mb2 = (const float*)d_in[12];
  const float* g_in  = (const float*)d_in[13];
  const float* be_in = (const float*)d_in[14];
  const float* g_sl  = (const float*)d_in[15];
  const float* be_sl = (const float*)d_in[16];
  const float* g_mu  = (const float*)d_in[17];
  const float* be_mu = (const float*)d_in[18];
  const float* oW1 = (const float*)d_in[19];
  const float* ob1 = (const float*)d_in[20];
  const float* oW2 = (const float*)d_in[21];
  const float* ob2 = (const float*)d_in[22];
  float* ws  = (float*)d_ws;
  float* out = (float*)d_out;
  (void)in_sizes; (void)n_in; (void)out_size; (void)ws_size;

  hipLaunchKernelGGL(tK, dim3(256), dim3(256), 0, stream,
                     Wq, Wk, Wv, Wih, Whh, mW1, mW2, oW1, oW2, ws);
  hipLaunchKernelGGL(k1K, dim3(256), dim3(512), 0, stream,
                     inputs, ws + OFF_WTKV, g_in, be_in, ws + OFF_K, ws + OFF_V);
  hipLaunchKernelGGL(s0K, dim3(64), dim3(256), 0, stream,
                     slots_in, g_sl, be_sl, ws + OFF_WQT, ws + OFF_MU, ws + OFF_WCOEF, ws + OFF_C);
  for (int s = 0; s < 4; ++s) {
    hipLaunchKernelGGL(pK, dim3(64, 4), dim3(512), 0, stream,
                       ws + OFF_K, ws + OFF_V, ws + OFF_WCOEF, ws + OFF_C,
                       ws + OFF_PART, ws + OFF_ATTNU, (s == 3) ? 1 : 0);
    hipLaunchKernelGGL(rK, dim3(64), dim3(512), 0, stream,
                       ws + OFF_PART, ws + OFF_WC, bih, bhh,
                       ws + OFF_MW1T, ws + OFF_MW2T, mb1, mb2, g_mu, be_mu,
                       g_sl, be_sl, ws + OFF_WQT,
                       ws + OFF_SLOTS, ws + OFF_MU, ws + OFF_WCOEF, ws + OFF_C, ws + OFF_RS);
  }
  hipLaunchKernelGGL(o1K, dim3(256), dim3(256), 0, stream,
                     ws + OFF_SLOTS, ws + OFF_OW1T, ws + OFF_OW2T, ob1, ws + OFF_OPART);
  hipLaunchKernelGGL(o2K, dim3(288), dim3(256), 0, stream,
                     ws + OFF_ATTNU, ws + OFF_RS, ws + OFF_OPART, ob2, out);
}